// Round 6
// baseline (111.446 us; speedup 1.0000x reference)
//
#include <hip/hip_runtime.h>

#define RTOT 12960      // 4 * 3240 rows
#define PAIRS 3240
#define NB_VAR 81
#define HID 256
#define EPS 1e-5f

#define BM 64
#define BN 64
#define NRT 203        // ceil(12960/64) row tiles
#define LDB 264        // sB row stride in bf16: 528 B/row -> bank offset 4/row, 2-way max (free)

using bf8   = __attribute__((ext_vector_type(8))) short;
using f32x4 = __attribute__((ext_vector_type(4))) float;

__device__ inline ushort f2bf(float f) {
    union { float f; unsigned u; } c; c.f = f;
    unsigned u = c.u + 0x7fffu + ((c.u >> 16) & 1u);
    return (ushort)(u >> 16);
}
__device__ inline float bf2f(ushort h) {
    union { unsigned u; float f; } c; c.u = (unsigned)h << 16;
    return c.f;
}
__device__ inline unsigned pk2(float a, float b) {
    return (unsigned)f2bf(a) | ((unsigned)f2bf(b) << 16);
}
// closed-form upper-tri pair from linear index p (0..3239): S(i)=(161i-i^2)/2
__device__ inline int2 pair_of(int p) {
    int i = (int)((161.0 - sqrt(25921.0 - 8.0 * (double)p)) * 0.5);
    if (i < 0) i = 0;
    while ((161 * (i + 1) - (i + 1) * (i + 1)) / 2 <= p) i++;
    while ((161 * i - i * i) / 2 > p) i--;
    int j = i + 1 + (p - (161 * i - i * i) / 2);
    return make_int2(i, j);
}

// ---------------- init: weights->bf16, pairs table, zero out-diagonal, input proj + stats0 ----------------
// stats zeroed by hipMemsetAsync before this kernel (atomicAdd race-free).
__global__ __launch_bounds__(256) void k_init(
        const float* __restrict__ x, const float* __restrict__ w_in,
        const float* __restrict__ b_in,
        const float* __restrict__ w1, const float* __restrict__ w2,
        const float* __restrict__ w_out, ushort* __restrict__ wbf,
        int2* __restrict__ pairs, float* __restrict__ out,
        ushort* __restrict__ h0, float* __restrict__ st) {
    __shared__ float feat[32][4];
    int tid = threadIdx.x;
    int gtid = blockIdx.x * 256 + tid;

    // weight conversion (grid-strided over 282880 elems)
    for (int i = gtid; i < 262144 + 81 * 256; i += 405 * 256) {
        float v;
        if (i < 131072)      v = w1[i];
        else if (i < 262144) v = w2[i - 131072];
        else                 v = w_out[i - 262144];
        wbf[i] = f2bf(v);
    }
    // zero diagonal blocks of out
    if (gtid < 4 * NB_VAR * 81) {
        int b = gtid / (NB_VAR * 81);
        int rem = gtid - b * (NB_VAR * 81);
        int i = rem / 81, t = rem - i * 81;
        out[((size_t)(b * NB_VAR + i) * NB_VAR + i) * 81 + t] = 0.f;
    }

    // input projection for rows r0..r0+31
    int r0 = blockIdx.x * 32;
    if (tid < 32) {
        int r = r0 + tid;
        int b = r / PAIRS, p = r - b * PAIRS;
        int2 ij = pair_of(p);
        if (r < PAIRS) pairs[r] = ij;      // table for k_gout (blocks 0..101 cover all)
        const float* xb = x + b * NB_VAR * 2;
        feat[tid][0] = xb[ij.x * 2 + 0];
        feat[tid][1] = xb[ij.x * 2 + 1];
        feat[tid][2] = xb[ij.y * 2 + 0];
        feat[tid][3] = xb[ij.y * 2 + 1];
    }
    __syncthreads();
    float4 w = ((const float4*)w_in)[tid];
    float bi = b_in[tid];
    float s = 0.f, s2 = 0.f;
    for (int t = 0; t < 32; t++) {
        float v = fmaf(feat[t][0], w.x, fmaf(feat[t][1], w.y,
                  fmaf(feat[t][2], w.z, fmaf(feat[t][3], w.w, bi))));
        v = fmaxf(v, 0.f);
        h0[(size_t)(r0 + t) * HID + tid] = f2bf(v);
        s += v; s2 += v * v;
    }
    atomicAdd(&st[tid], s);
    atomicAdd(&st[HID + tid], s2);
}

// ---------------- MFMA GEMM, barrier-free K-loop ----------------
// A-fragments loaded per-lane from global (L2-resident), BN+ReLU in registers.
// B staged once in LDS. Y = relu(bn(X)) @ W^T + bias (+res); col stats to stout.
__global__ __launch_bounds__(256) void k_gemm(
        const ushort* __restrict__ X, const float* __restrict__ stin,
        const float* __restrict__ g, const float* __restrict__ beta,
        const ushort* __restrict__ Wb, const float* __restrict__ bias,
        const ushort* __restrict__ res, ushort* __restrict__ Y,
        float* __restrict__ stout) {
    __shared__ ushort sB[BN * LDB];
    __shared__ float sS[HID], sT[HID];
    __shared__ float sCS[2][BN], sCQ[2][BN];

    int tid = threadIdx.x;
    {   // BN coefficients
        float sum = stin[tid], sq = stin[HID + tid];
        float m = sum * (1.f / RTOT);
        float v = sq * (1.f / RTOT) - m * m;
        float sc = g[tid] * rsqrtf(v + EPS);
        sS[tid] = sc;
        sT[tid] = fmaf(-m, sc, beta[tid]);
    }
    int bm0 = blockIdx.x * BM;
    int bn0 = blockIdx.y * BN;
    {   // stage whole B tile: 64 rows x 256 k
        int row = tid >> 2, cq = tid & 3;
#pragma unroll
        for (int s = 0; s < 8; s++) {
            int col = cq * 8 + s * 32;
            uint4 wv = *(const uint4*)(Wb + (size_t)(bn0 + row) * HID + col);
            *(uint4*)&sB[row * LDB + col] = wv;
        }
    }
    __syncthreads();

    int lane = tid & 63, wid = tid >> 6;
    int wr = wid >> 1, wc = wid & 1;
    int r16 = lane & 15, kq = lane >> 4;

    f32x4 acc[2][2] = {};
    int ar0 = min(bm0 + wr * 32 + r16, RTOT - 1);
    int ar1 = min(bm0 + wr * 32 + 16 + r16, RTOT - 1);

#pragma unroll
    for (int kk = 0; kk < 8; kk++) {
        int kst = kk * 32 + kq * 8;
        float4 s0 = *(const float4*)&sS[kst], s1 = *(const float4*)&sS[kst + 4];
        float4 t0 = *(const float4*)&sT[kst], t1 = *(const float4*)&sT[kst + 4];
        bf8 af[2];
#pragma unroll
        for (int m = 0; m < 2; m++) {
            ushort xv[8];
            *(uint4*)xv = *(const uint4*)(X + (size_t)(m ? ar1 : ar0) * HID + kst);
            unsigned pk[4];
            pk[0] = pk2(fmaxf(fmaf(bf2f(xv[0]), s0.x, t0.x), 0.f),
                        fmaxf(fmaf(bf2f(xv[1]), s0.y, t0.y), 0.f));
            pk[1] = pk2(fmaxf(fmaf(bf2f(xv[2]), s0.z, t0.z), 0.f),
                        fmaxf(fmaf(bf2f(xv[3]), s0.w, t0.w), 0.f));
            pk[2] = pk2(fmaxf(fmaf(bf2f(xv[4]), s1.x, t1.x), 0.f),
                        fmaxf(fmaf(bf2f(xv[5]), s1.y, t1.y), 0.f));
            pk[3] = pk2(fmaxf(fmaf(bf2f(xv[6]), s1.z, t1.z), 0.f),
                        fmaxf(fmaf(bf2f(xv[7]), s1.w, t1.w), 0.f));
            af[m] = *(bf8*)pk;
        }
        bf8 bfr[2];
#pragma unroll
        for (int n = 0; n < 2; n++)
            bfr[n] = *(const bf8*)&sB[(wc * 32 + n * 16 + r16) * LDB + kst];
#pragma unroll
        for (int m = 0; m < 2; m++)
#pragma unroll
            for (int n = 0; n < 2; n++)
                acc[m][n] = __builtin_amdgcn_mfma_f32_16x16x32_bf16(af[m], bfr[n], acc[m][n], 0, 0, 0);
    }

    // epilogue: bias (+res), store bf16, column stats
    int rb = bm0 + wr * 32;
    int cb = bn0 + wc * 32;
    float csum[2] = {0.f, 0.f}, csq[2] = {0.f, 0.f};
#pragma unroll
    for (int n = 0; n < 2; n++) {
        int col = cb + n * 16 + r16;
        float bv = bias[col];
#pragma unroll
        for (int m = 0; m < 2; m++) {
#pragma unroll
            for (int i = 0; i < 4; i++) {
                int r = rb + m * 16 + kq * 4 + i;
                if (r < RTOT) {
                    float v = acc[m][n][i] + bv;
                    if (res) v += bf2f(res[(size_t)r * HID + col]);
                    Y[(size_t)r * HID + col] = f2bf(v);
                    csum[n] += v; csq[n] += v * v;
                }
            }
        }
    }
#pragma unroll
    for (int n = 0; n < 2; n++) {
        float s = csum[n], q = csq[n];
        s += __shfl_xor(s, 16); q += __shfl_xor(q, 16);
        s += __shfl_xor(s, 32); q += __shfl_xor(q, 32);
        if (lane < 16) {
            int lc = wc * 32 + n * 16 + lane;
            sCS[wr][lc] = s; sCQ[wr][lc] = q;
        }
    }
    __syncthreads();
    if (tid < 2 * BN) {
        int col = tid & (BN - 1), q = tid >> 6;
        float v = q ? (sCQ[0][col] + sCQ[1][col]) : (sCS[0][col] + sCS[1][col]);
        atomicAdd(&stout[q * HID + bn0 + col], v);
    }
}

// ---------------- final GEMM (N=81), barrier-free K-loop, fused symmetric scatter ----------------
__global__ __launch_bounds__(256) void k_gout(
        const ushort* __restrict__ X, const float* __restrict__ stin,
        const float* __restrict__ g, const float* __restrict__ beta,
        const ushort* __restrict__ Wb, const float* __restrict__ b_out,
        const int2* __restrict__ pairs, float* __restrict__ out) {
    __shared__ ushort sB[BN * LDB];
    __shared__ float sS[HID], sT[HID];

    int tid = threadIdx.x;
    {
        float sum = stin[tid], sq = stin[HID + tid];
        float m = sum * (1.f / RTOT);
        float v = sq * (1.f / RTOT) - m * m;
        float sc = g[tid] * rsqrtf(v + EPS);
        sS[tid] = sc;
        sT[tid] = fmaf(-m, sc, beta[tid]);
    }
    int bm0 = blockIdx.x * BM;
    int bn0 = blockIdx.y * BN;
    {
        int row = tid >> 2, cq = tid & 3;
        int gn = bn0 + row; gn = gn < 81 ? gn : 80;
#pragma unroll
        for (int s = 0; s < 8; s++) {
            int col = cq * 8 + s * 32;
            uint4 wv = *(const uint4*)(Wb + (size_t)gn * HID + col);
            *(uint4*)&sB[row * LDB + col] = wv;
        }
    }
    __syncthreads();

    int lane = tid & 63, wid = tid >> 6;
    int wr = wid >> 1, wc = wid & 1;
    int r16 = lane & 15, kq = lane >> 4;

    f32x4 acc[2][2] = {};
    int ar0 = min(bm0 + wr * 32 + r16, RTOT - 1);
    int ar1 = min(bm0 + wr * 32 + 16 + r16, RTOT - 1);

#pragma unroll
    for (int kk = 0; kk < 8; kk++) {
        int kst = kk * 32 + kq * 8;
        float4 s0 = *(const float4*)&sS[kst], s1 = *(const float4*)&sS[kst + 4];
        float4 t0 = *(const float4*)&sT[kst], t1 = *(const float4*)&sT[kst + 4];
        bf8 af[2];
#pragma unroll
        for (int m = 0; m < 2; m++) {
            ushort xv[8];
            *(uint4*)xv = *(const uint4*)(X + (size_t)(m ? ar1 : ar0) * HID + kst);
            unsigned pk[4];
            pk[0] = pk2(fmaxf(fmaf(bf2f(xv[0]), s0.x, t0.x), 0.f),
                        fmaxf(fmaf(bf2f(xv[1]), s0.y, t0.y), 0.f));
            pk[1] = pk2(fmaxf(fmaf(bf2f(xv[2]), s0.z, t0.z), 0.f),
                        fmaxf(fmaf(bf2f(xv[3]), s0.w, t0.w), 0.f));
            pk[2] = pk2(fmaxf(fmaf(bf2f(xv[4]), s1.x, t1.x), 0.f),
                        fmaxf(fmaf(bf2f(xv[5]), s1.y, t1.y), 0.f));
            pk[3] = pk2(fmaxf(fmaf(bf2f(xv[6]), s1.z, t1.z), 0.f),
                        fmaxf(fmaf(bf2f(xv[7]), s1.w, t1.w), 0.f));
            af[m] = *(bf8*)pk;
        }
        bf8 bfr[2];
#pragma unroll
        for (int n = 0; n < 2; n++)
            bfr[n] = *(const bf8*)&sB[(wc * 32 + n * 16 + r16) * LDB + kst];
#pragma unroll
        for (int m = 0; m < 2; m++)
#pragma unroll
            for (int n = 0; n < 2; n++)
                acc[m][n] = __builtin_amdgcn_mfma_f32_16x16x32_bf16(af[m], bfr[n], acc[m][n], 0, 0, 0);
    }

    int rb = bm0 + wr * 32;
    int cb = bn0 + wc * 32;
    int tcol[2], ttr[2]; float bv[2]; bool tok[2];
#pragma unroll
    for (int n = 0; n < 2; n++) {
        int t = cb + n * 16 + r16;
        tok[n] = t < 81;
        int tc = tok[n] ? t : 0;
        tcol[n] = tc;
        int gi = tc / 9, gj = tc - gi * 9;
        ttr[n] = gj * 9 + gi;
        bv[n] = b_out[tc];
    }
#pragma unroll
    for (int m = 0; m < 2; m++) {
#pragma unroll
        for (int i = 0; i < 4; i++) {
            int r = rb + m * 16 + kq * 4 + i;
            if (r >= RTOT) continue;
            int b = r / PAIRS, p = r - b * PAIRS;
            int2 ij = pairs[p];
            size_t base1 = ((size_t)(b * NB_VAR + ij.x) * NB_VAR + ij.y) * 81;
            size_t base2 = ((size_t)(b * NB_VAR + ij.y) * NB_VAR + ij.x) * 81;
#pragma unroll
            for (int n = 0; n < 2; n++) {
                if (!tok[n]) continue;
                float v = acc[m][n][i] + bv[n];
                out[base1 + tcol[n]] = v;
                out[base2 + ttr[n]] = v;
            }
        }
    }
}

extern "C" void kernel_launch(void* const* d_in, const int* in_sizes, int n_in,
                              void* d_out, int out_size, void* d_ws, size_t ws_size,
                              hipStream_t stream) {
    const float* x     = (const float*)d_in[0];
    const float* w_in  = (const float*)d_in[1];
    const float* b_in  = (const float*)d_in[2];
    const float* g1    = (const float*)d_in[3];
    const float* beta1 = (const float*)d_in[4];
    const float* w1    = (const float*)d_in[5];
    const float* bias1 = (const float*)d_in[6];
    const float* g2    = (const float*)d_in[7];
    const float* beta2 = (const float*)d_in[8];
    const float* w2    = (const float*)d_in[9];
    const float* bias2 = (const float*)d_in[10];
    const float* fg    = (const float*)d_in[11];
    const float* fbeta = (const float*)d_in[12];
    const float* w_out = (const float*)d_in[13];
    const float* b_out = (const float*)d_in[14];
    float* out = (float*)d_out;

    ushort* buf0 = (ushort*)d_ws;
    ushort* buf1 = buf0 + (size_t)RTOT * HID;
    ushort* buf2 = buf1 + (size_t)RTOT * HID;
    ushort* wbf  = buf2 + (size_t)RTOT * HID;   // 5*65536 elems
    float* stats = (float*)(wbf + 5 * 65536);
    int2*  pairs = (int2*)(stats + 5 * 512);
    // wbf layout: w1_0 @0, w1_1 @65536, w2_0 @131072, w2_1 @196608, w_out @262144

    hipMemsetAsync(stats, 0, 5 * 512 * sizeof(float), stream);
    k_init<<<405, 256, 0, stream>>>(x, w_in, b_in, w1, w2, w_out, wbf,
                                    pairs, out, buf0, stats + 0 * 512);

    dim3 gmid(NRT, HID / BN);   // (203, 4)
    dim3 gfin(NRT, 2);          // (203, 2): cols 0-63 / 64-80

    k_gemm<<<gmid, 256, 0, stream>>>(buf0, stats + 0 * 512, g1, beta1,
                                     wbf + 0 * 65536, bias1, nullptr, buf1, stats + 1 * 512);
    k_gemm<<<gmid, 256, 0, stream>>>(buf1, stats + 1 * 512, g2, beta2,
                                     wbf + 2 * 65536, bias2, buf0, buf2, stats + 2 * 512);
    k_gemm<<<gmid, 256, 0, stream>>>(buf2, stats + 2 * 512, g1 + HID, beta1 + HID,
                                     wbf + 1 * 65536, bias1 + HID, nullptr, buf1, stats + 3 * 512);
    k_gemm<<<gmid, 256, 0, stream>>>(buf1, stats + 3 * 512, g2 + HID, beta2 + HID,
                                     wbf + 3 * 65536, bias2 + HID, buf2, buf0, stats + 4 * 512);
    k_gout<<<gfin, 256, 0, stream>>>(buf0, stats + 4 * 512, fg, fbeta,
                                     wbf + 4 * 65536, b_out, pairs, out);
}